// Round 3
// baseline (445.954 us; speedup 1.0000x reference)
//
#include <hip/hip_runtime.h>
#include <cstdint>

#define M_DIM 8192
#define K_DIM 4096
#define N_DIM 4096
#define NKT   32     // K-tiles of 128 (= one weight-scale block each)

typedef int   v4i  __attribute__((ext_vector_type(4)));
typedef int   v16i __attribute__((ext_vector_type(16)));
typedef float v4f  __attribute__((ext_vector_type(4)));

__device__ __forceinline__ void gload_lds16(const void* g, void* l) {
  __builtin_amdgcn_global_load_lds(
      (const __attribute__((address_space(1))) void*)g,
      (__attribute__((address_space(3))) void*)l, 16, 0, 0);
}

// Fragment-packed operand layout (both xq and wq):
//   chunk(b32, kt, k, l) at offset ((b32*32 + kt)*4 + k)*1024 + l*16
//   holds row (b32*32 + (l&31)), K-bytes kt*128 + (2k + (l>>5))*16 .. +16
// i.e. exactly the mfma_i32_32x32x32_i8 per-lane operand. GEMM-side loads and
// ds_reads are then wave-uniform-base + lane*16: coalesced 1KB instructions,
// LDS conflict-free by construction (R2's 1.26e7 conflicts came from the
// row-major + XOR-swizzle layout at 32-row fragment granularity).

// ---- Kernel 0: prep = per-row activation quant (blocks 0..M-1) + W repack ----
__global__ __launch_bounds__(256) void prep(
    const float* __restrict__ x, const int* __restrict__ w32,
    int8_t* __restrict__ xq, float* __restrict__ xs, int8_t* __restrict__ wq) {
  const int tid = threadIdx.x;
  if (blockIdx.x < M_DIM) {
    // per-row dynamic int8 quantization; thread t owns elems t*16..t*16+15
    const int row = blockIdx.x;
    const float4* xr = (const float4*)(x + (size_t)row * K_DIM);
    float4 v[4];
    float amax = 0.f;
#pragma unroll
    for (int i = 0; i < 4; ++i) {
      v[i] = xr[tid * 4 + i];  // wave reads 4KB contiguous
      amax = fmaxf(amax, fmaxf(fmaxf(fabsf(v[i].x), fabsf(v[i].y)),
                               fmaxf(fabsf(v[i].z), fabsf(v[i].w))));
    }
#pragma unroll
    for (int off = 32; off > 0; off >>= 1)
      amax = fmaxf(amax, __shfl_xor(amax, off, 64));
    __shared__ float red[4];
    if ((tid & 63) == 0) red[tid >> 6] = amax;
    __syncthreads();
    amax = fmaxf(fmaxf(red[0], red[1]), fmaxf(red[2], red[3]));
    amax = fmaxf(amax, 1e-6f);
    const float s   = amax / 127.0f;
    const float inv = 127.0f / amax;
    if (tid == 0) xs[row] = s;

    int w[4];
#pragma unroll
    for (int i = 0; i < 4; ++i) {
      int q0 = (int)fminf(fmaxf(rintf(v[i].x * inv), -128.f), 127.f);
      int q1 = (int)fminf(fmaxf(rintf(v[i].y * inv), -128.f), 127.f);
      int q2 = (int)fminf(fmaxf(rintf(v[i].z * inv), -128.f), 127.f);
      int q3 = (int)fminf(fmaxf(rintf(v[i].w * inv), -128.f), 127.f);
      w[i] = (q0 & 255) | ((q1 & 255) << 8) | ((q2 & 255) << 16) | ((q3 & 255) << 24);
    }
    // thread t = kt*8 + c owns chunk c of K-tile kt (elems t*16.. = kt*128+c*16..)
    const int kt = tid >> 3, c = tid & 7;
    const size_t doff =
        ((((size_t)(row >> 5) * 32 + kt) * 4 + (c >> 1)) * 64 + (row & 31) + 32 * (c & 1)) * 16;
    v4i ov = {w[0], w[1], w[2], w[3]};
    *(v4i*)(xq + doff) = ov;
  } else {
    // weight repack: int32-materialized [OUT][IN] -> fragment-packed int8
    const size_t t = (size_t)(blockIdx.x - M_DIM) * 256 + tid;
    const int l   = (int)(t & 63);
    const int k   = (int)((t >> 6) & 3);
    const int kt  = (int)((t >> 8) & 31);
    const int n32 = (int)(t >> 13);
    const int row = n32 * 32 + (l & 31);
    const int col = kt * 128 + (2 * k + (l >> 5)) * 16;
    const int4* src = (const int4*)(w32 + (size_t)row * K_DIM + col);  // 64B/thread, each read once
    int o[4];
#pragma unroll
    for (int q = 0; q < 4; ++q) {
      const int4 e = src[q];
      o[q] = (e.x & 255) | ((e.y & 255) << 8) | ((e.z & 255) << 16) | ((e.w & 255) << 24);
    }
    v4i ov = {o[0], o[1], o[2], o[3]};
    *(v4i*)(wq + t * 16) = ov;  // dst fully coalesced
  }
}

// ---------------- Kernel 1: int8 block-scaled GEMM, 256x256 -----------------
// 8 waves (2M x 4N), wave tile 128x64 = 4(m) x 2(n) of 32x32x32 i8 MFMA.
// A: fragment-packed global -> LDS (2x32KB dbuf) via global_load_lds, read as
//    lane-linear ds_read_b128 (conflict-free by construction).
// B: fragment-packed global -> REGISTERS directly (8 coalesced 1KB loads /
//    wave / ktile), prefetched in-place after last use; no LDS at all.
// Barrier: raw s_barrier + counted vmcnt(10) (T4): only the 4 staging
// global_load_lds must retire at the barrier; the 8 B + 2 scale prefetches
// stay in flight across it. sched_barrier(0) after staging pins issue order
// so the vmcnt count is sound.
// Per-CU per-ktile: MFMA 2330 cyc (floor), LDS ~1500, VMEM ~1500 -> MFMA-paced.
__global__ __launch_bounds__(512, 2) void gemm_q8(
    const int8_t* __restrict__ xq, const int8_t* __restrict__ wq,
    const float* __restrict__ wscale, const float* __restrict__ xs,
    const float* __restrict__ bias, float* __restrict__ out) {
  __shared__ int8_t lA[2][32768];  // [buf][m32 0..7][k 0..3][lane][16B]

  const int tid = threadIdx.x;
  const int lane = tid & 63;
  const int wv = tid >> 6;
  const int m0 = blockIdx.x * 256;
  const int n0 = blockIdx.y * 256;
  const int wm = (wv >> 2) << 7;  // wave m-offset: 0/128
  const int wn = (wv & 3) << 6;   // wave n-offset: 0/64/128/192
  const int l31 = lane & 31;
  const int hi = lane >> 5;

  // A staging: thread t stages m32-block (t>>6), lane slot (t&63), round p = k
  const size_t stageBase =
      ((size_t)((m0 >> 5) + (tid >> 6))) * 131072 + (size_t)(tid & 63) * 16;
  const int dstoff = (tid >> 6) * 4096 + (tid & 63) * 16;

  // B fragment bases for the wave's two 32-col tiles
  const int n32_0 = (n0 >> 5) + ((wv & 3) << 1);
  const int8_t* gb0 = wq + (size_t)n32_0 * 131072 + lane * 16;
  const int8_t* gb1 = gb0 + 131072;

  // A ds_read base: mtile i -> lA[d] + aBase + i*4096 + k*1024
  const int aBase = ((wv >> 2) * 4) * 4096 + lane * 16;

  float facc[4][2][16];
#pragma unroll
  for (int i = 0; i < 4; ++i)
#pragma unroll
    for (int j = 0; j < 2; ++j)
#pragma unroll
      for (int r = 0; r < 16; ++r) facc[i][j][r] = 0.f;

  const float* wsp = wscale + n0 + wn + l31;

  // prologue: stage A tile 0, load B tile 0 + scales, full drain once
#pragma unroll
  for (int p = 0; p < 4; ++p)
    gload_lds16(xq + stageBase + (size_t)p * 1024, &lA[0][dstoff + p * 1024]);
  v4i bcur[2][4];
#pragma unroll
  for (int k = 0; k < 4; ++k) {
    bcur[0][k] = *(const v4i*)(gb0 + k * 1024);
    bcur[1][k] = *(const v4i*)(gb1 + k * 1024);
  }
  float ws0 = wsp[0];
  float ws1 = wsp[32];
  __syncthreads();

  for (int kt = 0; kt < NKT; ++kt) {
    const int d = kt & 1;
    const int kn = (kt + 1) & (NKT - 1);  // last iter re-stages tile 0: harmless

    // stage next A tile into the other buffer (4 gload_lds)
#pragma unroll
    for (int p = 0; p < 4; ++p)
      gload_lds16(xq + stageBase + (size_t)kn * 4096 + (size_t)p * 1024,
                  &lA[d ^ 1][dstoff + p * 1024]);
    __builtin_amdgcn_sched_barrier(0);  // nothing later may hoist above staging

    const float cw0 = ws0, cw1 = ws1;  // this tile's scales (loaded last tile)
    const int8_t* pa = &lA[d][aBase];

    v4i acur[4];
#pragma unroll
    for (int k = 0; k < 4; ++k) acur[k] = *(const v4i*)(pa + k * 1024);

#pragma unroll
    for (int i = 0; i < 4; ++i) {
      v4i anxt[4];
      if (i < 3) {
#pragma unroll
        for (int k = 0; k < 4; ++k)
          anxt[k] = *(const v4i*)(pa + (i + 1) * 4096 + k * 1024);
      }
      v16i ic0 = {};
      v16i ic1 = {};
      __builtin_amdgcn_s_setprio(1);
#pragma unroll
      for (int k = 0; k < 4; ++k) {
        ic0 = __builtin_amdgcn_mfma_i32_32x32x32_i8(acur[k], bcur[0][k], ic0, 0, 0, 0);
        ic1 = __builtin_amdgcn_mfma_i32_32x32x32_i8(acur[k], bcur[1][k], ic1, 0, 0, 0);
      }
      __builtin_amdgcn_s_setprio(0);
      // per-block dequant (scale depends on column only)
#pragma unroll
      for (int r = 0; r < 16; ++r) facc[i][0][r] += cw0 * (float)ic0[r];
#pragma unroll
      for (int r = 0; r < 16; ++r) facc[i][1][r] += cw1 * (float)ic1[r];
      if (i < 3) {
#pragma unroll
        for (int k = 0; k < 4; ++k) acur[k] = anxt[k];
      }
    }

    // prefetch next tile's B + scales in place (after last bcur use);
    // these 10 loads stay in flight across the barrier (counted vmcnt)
#pragma unroll
    for (int k = 0; k < 4; ++k) {
      bcur[0][k] = *(const v4i*)(gb0 + (size_t)kn * 4096 + k * 1024);
      bcur[1][k] = *(const v4i*)(gb1 + (size_t)kn * 4096 + k * 1024);
    }
    ws0 = wsp[(size_t)kn * N_DIM];
    ws1 = wsp[(size_t)kn * N_DIM + 32];

    __builtin_amdgcn_sched_barrier(0);
    // wait only for the 4 staging gload_lds (oldest); 8 B + 2 ws may remain
    asm volatile("s_waitcnt vmcnt(10)" ::: "memory");
    __builtin_amdgcn_s_barrier();
    __builtin_amdgcn_sched_barrier(0);
  }

  // epilogue: out[m,n] = facc * xs[m] + bias[n]
  // 32x32 C layout: row = (r&3) + 8*(r>>2) + 4*hi, col = l31
  const float bv0 = bias[n0 + wn + l31];
  const float bv1 = bias[n0 + wn + 32 + l31];
#pragma unroll
  for (int i = 0; i < 4; ++i) {
    const int rbase = m0 + wm + i * 32 + (hi << 2);
#pragma unroll
    for (int q = 0; q < 4; ++q) {
      const v4f xv = *(const v4f*)(xs + rbase + q * 8);
#pragma unroll
      for (int r4 = 0; r4 < 4; ++r4) {
        const int r = q * 4 + r4;
        float* op = out + (size_t)(rbase + q * 8 + r4) * N_DIM + n0 + wn + l31;
        op[0]  = facc[i][0][r] * xv[r4] + bv0;
        op[32] = facc[i][1][r] * xv[r4] + bv1;
      }
    }
  }
}

extern "C" void kernel_launch(void* const* d_in, const int* in_sizes, int n_in,
                              void* d_out, int out_size, void* d_ws, size_t ws_size,
                              hipStream_t stream) {
  const float* x      = (const float*)d_in[0];
  const int*   w32    = (const int*)d_in[1];
  const float* wscale = (const float*)d_in[2];
  const float* bias   = (const float*)d_in[3];
  float* out = (float*)d_out;

  int8_t* xq  = (int8_t*)d_ws;
  int8_t* wq8 = (int8_t*)d_ws + (size_t)M_DIM * K_DIM;
  float*  xs  = (float*)((char*)d_ws + (size_t)M_DIM * K_DIM + (size_t)N_DIM * K_DIM);

  // fused prep: quant rows (M blocks) + weight repack (N*K/16/256 blocks)
  const int packBlocks = (int)((size_t)N_DIM * K_DIM / 16 / 256);  // 4096
  prep<<<M_DIM + packBlocks, 256, 0, stream>>>(x, w32, xq, xs, wq8);
  dim3 grid(M_DIM / 256, N_DIM / 256);
  gemm_q8<<<grid, 512, 0, stream>>>(xq, wq8, wscale, xs, bias, out);
}

// Round 4
// 436.210 us; speedup vs baseline: 1.0223x; 1.0223x over previous
//
#include <hip/hip_runtime.h>
#include <cstdint>

#define M_DIM 8192
#define K_DIM 4096
#define N_DIM 4096
#define NKT   32     // K-tiles of 128 (= one weight-scale block each)

typedef int   v4i  __attribute__((ext_vector_type(4)));
typedef int   v16i __attribute__((ext_vector_type(16)));
typedef float v4f  __attribute__((ext_vector_type(4)));

__device__ __forceinline__ void gload_lds16(const void* g, void* l) {
  __builtin_amdgcn_global_load_lds(
      (const __attribute__((address_space(1))) void*)g,
      (__attribute__((address_space(3))) void*)l, 16, 0, 0);
}

// Fragment-packed operand layout (both xq and wq):
//   chunk(b32, kt, k, l) at offset ((b32*32 + kt)*4 + k)*1024 + l*16
//   holds row (b32*32 + (l&31)), K-bytes kt*128 + (2k + (l>>5))*16 .. +16
// i.e. exactly the mfma_i32_32x32x32_i8 per-lane operand. GEMM-side loads and
// ds_reads are then wave-uniform-base + lane*16: coalesced 1KB instructions,
// LDS conflict-free by construction (verified R3: SQ_LDS_BANK_CONFLICT = 0).

// ---- Kernel 0: prep = per-row activation quant (blocks 0..M-1) + W repack ----
__global__ __launch_bounds__(256) void prep(
    const float* __restrict__ x, const int* __restrict__ w32,
    int8_t* __restrict__ xq, float* __restrict__ xs, int8_t* __restrict__ wq) {
  const int tid = threadIdx.x;
  if (blockIdx.x < M_DIM) {
    // per-row dynamic int8 quantization; thread t owns elems t*16..t*16+15
    const int row = blockIdx.x;
    const float4* xr = (const float4*)(x + (size_t)row * K_DIM);
    float4 v[4];
    float amax = 0.f;
#pragma unroll
    for (int i = 0; i < 4; ++i) {
      v[i] = xr[tid * 4 + i];  // wave reads 4KB contiguous
      amax = fmaxf(amax, fmaxf(fmaxf(fabsf(v[i].x), fabsf(v[i].y)),
                               fmaxf(fabsf(v[i].z), fabsf(v[i].w))));
    }
#pragma unroll
    for (int off = 32; off > 0; off >>= 1)
      amax = fmaxf(amax, __shfl_xor(amax, off, 64));
    __shared__ float red[4];
    if ((tid & 63) == 0) red[tid >> 6] = amax;
    __syncthreads();
    amax = fmaxf(fmaxf(red[0], red[1]), fmaxf(red[2], red[3]));
    amax = fmaxf(amax, 1e-6f);
    const float s   = amax / 127.0f;
    const float inv = 127.0f / amax;
    if (tid == 0) xs[row] = s;

    int w[4];
#pragma unroll
    for (int i = 0; i < 4; ++i) {
      int q0 = (int)fminf(fmaxf(rintf(v[i].x * inv), -128.f), 127.f);
      int q1 = (int)fminf(fmaxf(rintf(v[i].y * inv), -128.f), 127.f);
      int q2 = (int)fminf(fmaxf(rintf(v[i].z * inv), -128.f), 127.f);
      int q3 = (int)fminf(fmaxf(rintf(v[i].w * inv), -128.f), 127.f);
      w[i] = (q0 & 255) | ((q1 & 255) << 8) | ((q2 & 255) << 16) | ((q3 & 255) << 24);
    }
    // thread t = kt*8 + c owns chunk c of K-tile kt (elems t*16.. = kt*128+c*16..)
    const int kt = tid >> 3, c = tid & 7;
    const size_t doff =
        ((((size_t)(row >> 5) * 32 + kt) * 4 + (c >> 1)) * 64 + (row & 31) + 32 * (c & 1)) * 16;
    v4i ov = {w[0], w[1], w[2], w[3]};
    *(v4i*)(xq + doff) = ov;
  } else {
    // weight repack: int32-materialized [OUT][IN] -> fragment-packed int8
    const size_t t = (size_t)(blockIdx.x - M_DIM) * 256 + tid;
    const int l   = (int)(t & 63);
    const int k   = (int)((t >> 6) & 3);
    const int kt  = (int)((t >> 8) & 31);
    const int n32 = (int)(t >> 13);
    const int row = n32 * 32 + (l & 31);
    const int col = kt * 128 + (2 * k + (l >> 5)) * 16;
    const int4* src = (const int4*)(w32 + (size_t)row * K_DIM + col);  // 64B/thread, each read once
    int o[4];
#pragma unroll
    for (int q = 0; q < 4; ++q) {
      const int4 e = src[q];
      o[q] = (e.x & 255) | ((e.y & 255) << 8) | ((e.z & 255) << 16) | ((e.w & 255) << 24);
    }
    v4i ov = {o[0], o[1], o[2], o[3]};
    *(v4i*)(wq + t * 16) = ov;  // dst fully coalesced
  }
}

// ---------------- Kernel 1: int8 block-scaled GEMM, 256x256 -----------------
// 8 waves (2M x 4N), wave tile 128x64 = 4(m) x 2(n) of 32x32x32 i8 MFMA.
// A: fragment-packed global -> LDS (2x32KB dbuf) via global_load_lds, read as
//    lane-linear ds_read_b128 (conflict-free by construction, R3-verified 0).
// B: fragment-packed global -> registers (8 coalesced 1KB loads/wave/ktile),
//    prefetched in-place after last use; no LDS.
// R4 change (T15 at step granularity): the K-tile's 8 MFMA-steps
// (mtile i x j) ping-pong ic[2]; step s computes ic[s&1] (4-MFMA chain) while
// dequanting ic[1-(s&1)] from step s-1 (retired -> no RAW stall). Dequant VALU
// now fills the MFMA chain's dependency bubbles inside one wave instead of
// serializing after the cluster (R3: MFMA 2342 + VALU 2472 cyc/SIMD/ktile ran
// back-to-back -> 7125 cyc wall, MfmaUtil 33%). A-frags ping-pong the same way
// (prefetch i+1's ds_reads 2 steps early into the retired buffer). Zero extra
// registers: ic 32 + afr 32 + bcur 32 as before.
// Barrier: raw s_barrier + counted vmcnt(10): only the 4 staging gload_lds
// must retire; 8 B + 2 scale prefetches stay in flight across it.
__global__ __launch_bounds__(512, 2) void gemm_q8(
    const int8_t* __restrict__ xq, const int8_t* __restrict__ wq,
    const float* __restrict__ wscale, const float* __restrict__ xs,
    const float* __restrict__ bias, float* __restrict__ out) {
  __shared__ int8_t lA[2][32768];  // [buf][m32 0..7][k 0..3][lane][16B]

  const int tid = threadIdx.x;
  const int lane = tid & 63;
  const int wv = tid >> 6;
  const int m0 = blockIdx.x * 256;
  const int n0 = blockIdx.y * 256;
  const int wm = (wv >> 2) << 7;  // wave m-offset: 0/128
  const int wn = (wv & 3) << 6;   // wave n-offset: 0/64/128/192
  const int l31 = lane & 31;
  const int hi = lane >> 5;

  // A staging: thread t stages m32-block (t>>6), lane slot (t&63), round p = k
  const size_t stageBase =
      ((size_t)((m0 >> 5) + (tid >> 6))) * 131072 + (size_t)(tid & 63) * 16;
  const int dstoff = (tid >> 6) * 4096 + (tid & 63) * 16;

  // B fragment bases for the wave's two 32-col tiles
  const int n32_0 = (n0 >> 5) + ((wv & 3) << 1);
  const int8_t* gb0 = wq + (size_t)n32_0 * 131072 + lane * 16;
  const int8_t* gb1 = gb0 + 131072;

  // A ds_read base: mtile i -> lA[d] + aBase + i*4096 + k*1024
  const int aBase = ((wv >> 2) * 4) * 4096 + lane * 16;

  float facc[4][2][16];
#pragma unroll
  for (int i = 0; i < 4; ++i)
#pragma unroll
    for (int j = 0; j < 2; ++j)
#pragma unroll
      for (int r = 0; r < 16; ++r) facc[i][j][r] = 0.f;

  const float* wsp = wscale + n0 + wn + l31;

  // prologue: stage A tile 0, load B tile 0 + scales, full drain once
#pragma unroll
  for (int p = 0; p < 4; ++p)
    gload_lds16(xq + stageBase + (size_t)p * 1024, &lA[0][dstoff + p * 1024]);
  v4i bcur[2][4];
#pragma unroll
  for (int k = 0; k < 4; ++k) {
    bcur[0][k] = *(const v4i*)(gb0 + k * 1024);
    bcur[1][k] = *(const v4i*)(gb1 + k * 1024);
  }
  float ws0 = wsp[0];
  float ws1 = wsp[32];
  __syncthreads();

  for (int kt = 0; kt < NKT; ++kt) {
    const int d = kt & 1;
    const int kn = (kt + 1) & (NKT - 1);  // last iter re-stages tile 0: harmless

    // stage next A tile into the other buffer (4 gload_lds)
#pragma unroll
    for (int p = 0; p < 4; ++p)
      gload_lds16(xq + stageBase + (size_t)kn * 4096 + (size_t)p * 1024,
                  &lA[d ^ 1][dstoff + p * 1024]);
    __builtin_amdgcn_sched_barrier(0);  // nothing later may hoist above staging

    const float cw0 = ws0, cw1 = ws1;  // this tile's scales (loaded last tile)
    const int8_t* pa = &lA[d][aBase];

    v4i afr[2][4];
    v16i ic[2];
#pragma unroll
    for (int k = 0; k < 4; ++k) afr[0][k] = *(const v4i*)(pa + k * 1024);

    __builtin_amdgcn_s_setprio(1);
#pragma unroll
    for (int s = 0; s < 8; ++s) {
      const int i = s >> 1, j = s & 1;
      // prefetch mtile i+1's A frags into the retired buffer, 2 steps early
      if (j == 0 && i < 3) {
#pragma unroll
        for (int k = 0; k < 4; ++k)
          afr[(i + 1) & 1][k] = *(const v4i*)(pa + (i + 1) * 4096 + k * 1024);
      }
      // 4-MFMA chain into ic[j]
      v16i t = {};
#pragma unroll
      for (int k = 0; k < 4; ++k)
        t = __builtin_amdgcn_mfma_i32_32x32x32_i8(afr[i & 1][k], bcur[j][k], t, 0, 0, 0);
      ic[j] = t;
      // dequant the PREVIOUS step's ic (retired): fills this chain's bubbles
      if (s > 0) {
        const int pi = (s - 1) >> 1, pj = (s - 1) & 1;
        const float w = pj ? cw1 : cw0;
#pragma unroll
        for (int r = 0; r < 16; ++r) facc[pi][pj][r] += w * (float)ic[pj][r];
      }
    }
    __builtin_amdgcn_s_setprio(0);

    // prefetch next tile's B + scales in place (after last bcur use);
    // overlaps the tail dequant below and stays in flight across the barrier
#pragma unroll
    for (int k = 0; k < 4; ++k) {
      bcur[0][k] = *(const v4i*)(gb0 + (size_t)kn * 4096 + k * 1024);
      bcur[1][k] = *(const v4i*)(gb1 + (size_t)kn * 4096 + k * 1024);
    }
    ws0 = wsp[(size_t)kn * N_DIM];
    ws1 = wsp[(size_t)kn * N_DIM + 32];

    // tail dequant: step 7's ic[1]
#pragma unroll
    for (int r = 0; r < 16; ++r) facc[3][1][r] += cw1 * (float)ic[1][r];

    __builtin_amdgcn_sched_barrier(0);
    // wait only for the 4 staging gload_lds (oldest); 8 B + 2 ws may remain
    asm volatile("s_waitcnt vmcnt(10)" ::: "memory");
    __builtin_amdgcn_s_barrier();
    __builtin_amdgcn_sched_barrier(0);
  }

  // epilogue: out[m,n] = facc * xs[m] + bias[n]
  // 32x32 C layout: row = (r&3) + 8*(r>>2) + 4*hi, col = l31
  const float bv0 = bias[n0 + wn + l31];
  const float bv1 = bias[n0 + wn + 32 + l31];
#pragma unroll
  for (int i = 0; i < 4; ++i) {
    const int rbase = m0 + wm + i * 32 + (hi << 2);
#pragma unroll
    for (int q = 0; q < 4; ++q) {
      const v4f xv = *(const v4f*)(xs + rbase + q * 8);
#pragma unroll
      for (int r4 = 0; r4 < 4; ++r4) {
        const int r = q * 4 + r4;
        float* op = out + (size_t)(rbase + q * 8 + r4) * N_DIM + n0 + wn + l31;
        op[0]  = facc[i][0][r] * xv[r4] + bv0;
        op[32] = facc[i][1][r] * xv[r4] + bv1;
      }
    }
  }
}

extern "C" void kernel_launch(void* const* d_in, const int* in_sizes, int n_in,
                              void* d_out, int out_size, void* d_ws, size_t ws_size,
                              hipStream_t stream) {
  const float* x      = (const float*)d_in[0];
  const int*   w32    = (const int*)d_in[1];
  const float* wscale = (const float*)d_in[2];
  const float* bias   = (const float*)d_in[3];
  float* out = (float*)d_out;

  int8_t* xq  = (int8_t*)d_ws;
  int8_t* wq8 = (int8_t*)d_ws + (size_t)M_DIM * K_DIM;
  float*  xs  = (float*)((char*)d_ws + (size_t)M_DIM * K_DIM + (size_t)N_DIM * K_DIM);

  // fused prep: quant rows (M blocks) + weight repack (N*K/16/256 blocks)
  const int packBlocks = (int)((size_t)N_DIM * K_DIM / 16 / 256);  // 4096
  prep<<<M_DIM + packBlocks, 256, 0, stream>>>(x, w32, xq, xs, wq8);
  dim3 grid(M_DIM / 256, N_DIM / 256);
  gemm_q8<<<grid, 512, 0, stream>>>(xq, wq8, wscale, xs, bias, out);
}